// Round 5
// baseline (238.454 us; speedup 1.0000x reference)
//
#include <hip/hip_runtime.h>

#define SEQ   2048
#define DM    1024
#define NH    16
#define DK    64
#define BATCH 2
#define M_TOT 4096
#define ATT_STR 72   // LDS row stride (bf16 elems): 144 B, 16B-aligned

typedef __attribute__((ext_vector_type(8))) short bf16x8;
typedef __attribute__((ext_vector_type(4))) float f32x4;
typedef unsigned short u16;

__device__ inline u16 f2b(float f) {               // f32 -> bf16 bits (RNE)
    union { float f; unsigned u; } x; x.f = f;
    return (u16)((x.u + 0x7FFFu + ((x.u >> 16) & 1u)) >> 16);
}

__device__ inline void async_cp16(const u16* g, u16* l) {
    __builtin_amdgcn_global_load_lds(
        (const __attribute__((address_space(1))) unsigned int*)g,
        (__attribute__((address_space(3))) unsigned int*)l, 16, 0, 0);
}

// ---------------------------------------------------------------------------
// x [4096][1024] f32 -> bf16
// ---------------------------------------------------------------------------
__global__ __launch_bounds__(256) void cast_x(
    const float4* __restrict__ x, ushort4* __restrict__ xb)
{
    int gid = blockIdx.x * 256 + threadIdx.x;
    float4 v = x[gid];
    ushort4 o;
    o.x = f2b(v.x); o.y = f2b(v.y); o.z = f2b(v.z); o.w = f2b(v.w);
    xb[gid] = o;
}

// ---------------------------------------------------------------------------
// All four weights:  W [k][n] f32 -> Wt [n][k] bf16, z selects the weight.
// ---------------------------------------------------------------------------
__global__ __launch_bounds__(256) void transpose_cast4(
    const float* __restrict__ W0, const float* __restrict__ W1,
    const float* __restrict__ W2, const float* __restrict__ W3,
    u16* __restrict__ WtBase)
{
    __shared__ float tile[32][33];
    const int t = threadIdx.x;
    const int n0 = blockIdx.x << 5, k0 = blockIdx.y << 5, z = blockIdx.z;
    const float* W = (z == 0) ? W0 : (z == 1) ? W1 : (z == 2) ? W2 : W3;
    u16* Wt = WtBase + (size_t)z * DM * DM;
    #pragma unroll
    for (int i = 0; i < 4; ++i) {
        int idx = t + (i << 8); int r = idx >> 5, c = idx & 31;
        tile[r][c] = W[(size_t)(k0 + r) * DM + n0 + c];
    }
    __syncthreads();
    #pragma unroll
    for (int i = 0; i < 4; ++i) {
        int idx = t + (i << 8); int r = idx >> 5, c = idx & 31;
        Wt[(size_t)(n0 + r) * DM + k0 + c] = f2b(tile[c][r]);
    }
}

// ---------------------------------------------------------------------------
// MFMA GEMM:  C = A @ Bt^T + bias.  128x128 tile, BK=32, 4 waves.
// mode 1 (QKV, N=3072): out0=Q [bh][s][d], out1=K [bh][s][d], out2=Vt [bh][d][s]
//   Epilogue goes through a per-wave LDS strip so global stores coalesce.
// mode 0 (final, N=1024): out0 = f32 [M][1024], direct stores.
// ---------------------------------------------------------------------------
__global__ __launch_bounds__(256) void gemm_bt(
    const u16* __restrict__ A, const u16* __restrict__ Bt, int mode,
    const float* __restrict__ bias0, const float* __restrict__ bias1,
    const float* __restrict__ bias2,
    void* __restrict__ out0, void* __restrict__ out1, void* __restrict__ out2)
{
    __shared__ u16 sh[128 * 32 * 2];     // As | Bs, reused by the epilogue
    u16* As = sh;
    u16* Bs = sh + 128 * 32;
    const int t = threadIdx.x, wid = t >> 6, lane = t & 63;
    const int lr = lane & 15, quad = lane >> 4;
    const int m0 = blockIdx.y << 7, n0 = blockIdx.x << 7;
    const int wm = (wid & 1) << 6, wn = (wid >> 1) << 6;
    const int rowA = lane >> 2, colA = (lane & 3) << 3;

    f32x4 acc[4][4];
    #pragma unroll
    for (int i = 0; i < 4; ++i)
        #pragma unroll
        for (int j = 0; j < 4; ++j) acc[i][j] = (f32x4){0.f, 0.f, 0.f, 0.f};

    for (int k0 = 0; k0 < DM; k0 += 32) {
        #pragma unroll
        for (int i = 0; i < 2; ++i) {
            int ch = wid * 2 + i;
            async_cp16(A  + (size_t)(m0 + ch * 16 + rowA) * DM + k0 + colA,
                       As + ch * 16 * 32);
            async_cp16(Bt + (size_t)(n0 + ch * 16 + rowA) * DM + k0 + colA,
                       Bs + ch * 16 * 32);
        }
        __syncthreads();
        bf16x8 af[4], bfr[4];
        #pragma unroll
        for (int mt = 0; mt < 4; ++mt)
            af[mt] = *(const bf16x8*)(As + (wm + 16 * mt + lr) * 32 + quad * 8);
        #pragma unroll
        for (int nt = 0; nt < 4; ++nt)
            bfr[nt] = *(const bf16x8*)(Bs + (wn + 16 * nt + lr) * 32 + quad * 8);
        #pragma unroll
        for (int mt = 0; mt < 4; ++mt)
            #pragma unroll
            for (int nt = 0; nt < 4; ++nt)
                acc[mt][nt] = __builtin_amdgcn_mfma_f32_16x16x32_bf16(
                    af[mt], bfr[nt], acc[mt][nt], 0, 0, 0);
        __syncthreads();   // also guards sh reuse by the epilogue below
    }

    if (mode == 1) {
        // per-wave strip in sh: Q/K use [16 m][64 n] stride 72; V uses [64 n][16 m] stride 16
        u16* wstrip = sh + wid * 1152;
        const int ngb = n0 + wn;                 // 64-aligned
        const int which = ngb >> 10, nnb = ngb & 1023;
        const int h = nnb >> 6;
        const float* bp = (which == 0) ? bias0 : (which == 1) ? bias1 : bias2;
        float bias_v[4];
        #pragma unroll
        for (int nt = 0; nt < 4; ++nt) bias_v[nt] = bp[nnb + 16 * nt + lr];

        if (which < 2) {
            u16* dst = which ? (u16*)out1 : (u16*)out0;
            #pragma unroll
            for (int mt = 0; mt < 4; ++mt) {
                #pragma unroll
                for (int nt = 0; nt < 4; ++nt)
                    #pragma unroll
                    for (int r = 0; r < 4; ++r)
                        wstrip[(quad * 4 + r) * 72 + 16 * nt + lr] =
                            f2b(acc[mt][nt][r] + bias_v[nt]);
                asm volatile("s_waitcnt lgkmcnt(0)" ::: "memory");
                #pragma unroll
                for (int half = 0; half < 2; ++half) {
                    int id = lane + 64 * half;
                    int mloc = id >> 3, dl = (id & 7) << 3;
                    int m = m0 + wm + 16 * mt + mloc;
                    int b = m >> 11, s = m & (SEQ - 1);
                    *(uint4*)(dst + ((size_t)(b * NH + h) * SEQ + s) * DK + dl) =
                        *(const uint4*)(wstrip + mloc * 72 + dl);
                }
                asm volatile("s_waitcnt lgkmcnt(0)" ::: "memory");
            }
        } else {
            u16* dst = (u16*)out2;               // Vt [bh][d][s]
            #pragma unroll
            for (int mt = 0; mt < 4; ++mt) {
                #pragma unroll
                for (int nt = 0; nt < 4; ++nt)
                    #pragma unroll
                    for (int r = 0; r < 4; ++r)
                        wstrip[(16 * nt + lr) * 16 + quad * 4 + r] =
                            f2b(acc[mt][nt][r] + bias_v[nt]);
                asm volatile("s_waitcnt lgkmcnt(0)" ::: "memory");
                #pragma unroll
                for (int half = 0; half < 2; ++half) {
                    int id = lane + 64 * half;
                    int d = id >> 1, cho = (id & 1) << 3;
                    int m = m0 + wm + 16 * mt + cho;
                    int b = m >> 11, s = m & (SEQ - 1);
                    *(uint4*)(dst + ((size_t)(b * NH + h) * DK + d) * SEQ + s) =
                        *(const uint4*)(wstrip + d * 16 + cho);
                }
                asm volatile("s_waitcnt lgkmcnt(0)" ::: "memory");
            }
        }
    } else {
        float* O = (float*)out0;
        #pragma unroll
        for (int nt = 0; nt < 4; ++nt) {
            int ng = n0 + wn + 16 * nt + lr;
            float bv_ = bias0[ng];
            #pragma unroll
            for (int mt = 0; mt < 4; ++mt) {
                int mr = m0 + wm + 16 * mt + (quad << 2);
                f32x4 v = acc[mt][nt];
                O[(size_t)mr * DM + ng]       = v.x + bv_;
                O[(size_t)(mr + 1) * DM + ng] = v.y + bv_;
                O[(size_t)(mr + 2) * DM + ng] = v.z + bv_;
                O[(size_t)(mr + 3) * DM + ng] = v.w + bv_;
            }
        }
    }
}

// ---------------------------------------------------------------------------
// Flash attention, S^T formulation, 128 q-rows/block (32 q per wave).
//   Q,K: [bh][s][64] bf16; Vt: [bh][64][s] bf16; out A: [4096][1024] bf16.
// Wave w owns q-cols [32w, 32w+32) = two 16-wide N-tiles -> K/V fragments
// are reused x2 per ds_read.  Q^T fragments load direct from global once.
//   S^T = K.Q^T  (C/D col = q -> softmax in-lane + 2 shfl)
//   O^T = V^T.P^T (P^T via wave-private LDS rows, lgkmcnt-only sync)
// 2 barriers per K-tile. LDS = (64+64)*72*2 + 128*72*2 = 36.9 KB.
// ---------------------------------------------------------------------------
__global__ __launch_bounds__(256) void attn_mfma(
    const u16* __restrict__ Q, const u16* __restrict__ K,
    const u16* __restrict__ Vt, u16* __restrict__ A)
{
    __shared__ u16 Ks[64 * ATT_STR];    // [kr][d]
    __shared__ u16 Vs[64 * ATT_STR];    // [d][kr]
    __shared__ u16 Ps[128 * ATT_STR];   // P^T [q][kr], wave-private rows

    const int t = threadIdx.x, wid = t >> 6, lane = t & 63;
    const int lr = lane & 15, quad = lane >> 4;
    const int bh = blockIdx.x, q0 = blockIdx.y << 7;
    const u16* Kb = K  + (size_t)bh * SEQ * DK;
    const u16* Vb = Vt + (size_t)bh * DK * SEQ;

    // loop-invariant Q^T fragments (B-operand: lane lr = q, k = d)
    bf16x8 bQ[2][2];
    #pragma unroll
    for (int nq = 0; nq < 2; ++nq) {
        int q = q0 + 32 * wid + 16 * nq + lr;
        const u16* qp = Q + ((size_t)bh * SEQ + q) * DK + quad * 8;
        bQ[nq][0] = *(const bf16x8*)(qp);
        bQ[nq][1] = *(const bf16x8*)(qp + 32);
    }

    f32x4 O[4][2];
    #pragma unroll
    for (int mt = 0; mt < 4; ++mt)
        #pragma unroll
        for (int nq = 0; nq < 2; ++nq) O[mt][nq] = (f32x4){0.f, 0.f, 0.f, 0.f};
    float m_r[2] = {-1e30f, -1e30f}, l_r[2] = {0.f, 0.f};

    for (int kb = 0; kb < SEQ / 64; ++kb) {
        #pragma unroll
        for (int i = 0; i < 2; ++i) {
            int id = t + 256 * i; int r = id >> 3, c0 = (id & 7) << 3;
            *(uint4*)(Ks + r * ATT_STR + c0) =
                *(const uint4*)(Kb + (size_t)(kb * 64 + r) * DK + c0);
            *(uint4*)(Vs + r * ATT_STR + c0) =
                *(const uint4*)(Vb + (size_t)r * SEQ + kb * 64 + c0);
        }
        __syncthreads();                               // (a) KV published

        // ---- S^T = K.Q^T : m = kr (4 tiles), n = q (2 tiles), k = d ----
        f32x4 S[4][2];
        #pragma unroll
        for (int mt = 0; mt < 4; ++mt) {
            bf16x8 a0 = *(const bf16x8*)(Ks + (16 * mt + lr) * ATT_STR + quad * 8);
            bf16x8 a1 = *(const bf16x8*)(Ks + (16 * mt + lr) * ATT_STR + 32 + quad * 8);
            #pragma unroll
            for (int nq = 0; nq < 2; ++nq) {
                f32x4 s = (f32x4){0.f, 0.f, 0.f, 0.f};
                s = __builtin_amdgcn_mfma_f32_16x16x32_bf16(a0, bQ[nq][0], s, 0, 0, 0);
                s = __builtin_amdgcn_mfma_f32_16x16x32_bf16(a1, bQ[nq][1], s, 0, 0, 0);
                S[mt][nq] = s;
            }
        }

        // ---- online softmax per nq: 16 in-lane values, 2 shfl ----
        #pragma unroll
        for (int nq = 0; nq < 2; ++nq) {
            float mx = -1e30f;
            #pragma unroll
            for (int mt = 0; mt < 4; ++mt)
                #pragma unroll
                for (int r = 0; r < 4; ++r) mx = fmaxf(mx, S[mt][nq][r]);
            mx = fmaxf(mx, __shfl_xor(mx, 16));
            mx = fmaxf(mx, __shfl_xor(mx, 32));
            float nm = fmaxf(m_r[nq], 0.125f * mx);
            float alpha = __expf(m_r[nq] - nm);
            m_r[nq] = nm;
            float sum = 0.f;
            #pragma unroll
            for (int mt = 0; mt < 4; ++mt) {
                float e0 = __expf(fmaf(S[mt][nq][0], 0.125f, -nm));
                float e1 = __expf(fmaf(S[mt][nq][1], 0.125f, -nm));
                float e2 = __expf(fmaf(S[mt][nq][2], 0.125f, -nm));
                float e3 = __expf(fmaf(S[mt][nq][3], 0.125f, -nm));
                sum += (e0 + e1) + (e2 + e3);
                ushort4 pk;
                pk.x = f2b(e0); pk.y = f2b(e1); pk.z = f2b(e2); pk.w = f2b(e3);
                *(ushort4*)(Ps + (32 * wid + 16 * nq + lr) * ATT_STR
                               + 16 * mt + 4 * quad) = pk;
            }
            sum += __shfl_xor(sum, 16);
            sum += __shfl_xor(sum, 32);
            l_r[nq] = l_r[nq] * alpha + sum;
            #pragma unroll
            for (int mt = 0; mt < 4; ++mt) {
                O[mt][nq][0] *= alpha; O[mt][nq][1] *= alpha;
                O[mt][nq][2] *= alpha; O[mt][nq][3] *= alpha;
            }
        }
        asm volatile("s_waitcnt lgkmcnt(0)" ::: "memory");  // wave-private P rows

        // ---- O^T += V^T.P^T : m = d (4 tiles), n = q (2), k = kr (2) ----
        bf16x8 P0[2], P1[2];
        #pragma unroll
        for (int nq = 0; nq < 2; ++nq) {
            P0[nq] = *(const bf16x8*)(Ps + (32 * wid + 16 * nq + lr) * ATT_STR + quad * 8);
            P1[nq] = *(const bf16x8*)(Ps + (32 * wid + 16 * nq + lr) * ATT_STR + 32 + quad * 8);
        }
        #pragma unroll
        for (int mt = 0; mt < 4; ++mt) {
            bf16x8 v0 = *(const bf16x8*)(Vs + (16 * mt + lr) * ATT_STR + quad * 8);
            bf16x8 v1 = *(const bf16x8*)(Vs + (16 * mt + lr) * ATT_STR + 32 + quad * 8);
            #pragma unroll
            for (int nq = 0; nq < 2; ++nq) {
                O[mt][nq] = __builtin_amdgcn_mfma_f32_16x16x32_bf16(v0, P0[nq], O[mt][nq], 0, 0, 0);
                O[mt][nq] = __builtin_amdgcn_mfma_f32_16x16x32_bf16(v1, P1[nq], O[mt][nq], 0, 0, 0);
            }
        }
        __syncthreads();                               // (b) protect Ks/Vs
    }

    // epilogue: lane has O^T[d = 16mt+4quad+r][q]
    const int b = bh >> 4, h = bh & 15;
    #pragma unroll
    for (int nq = 0; nq < 2; ++nq) {
        int q = q0 + 32 * wid + 16 * nq + lr;
        float inv = 1.f / l_r[nq];
        #pragma unroll
        for (int mt = 0; mt < 4; ++mt) {
            ushort4 pk;
            pk.x = f2b(O[mt][nq][0] * inv); pk.y = f2b(O[mt][nq][1] * inv);
            pk.z = f2b(O[mt][nq][2] * inv); pk.w = f2b(O[mt][nq][3] * inv);
            *(ushort4*)(A + (size_t)(b * SEQ + q) * DM + h * DK + 16 * mt + 4 * quad) = pk;
        }
    }
}

// ---------------------------------------------------------------------------
extern "C" void kernel_launch(void* const* d_in, const int* in_sizes, int n_in,
                              void* d_out, int out_size, void* d_ws, size_t ws_size,
                              hipStream_t stream)
{
    const float* x  = (const float*)d_in[0];
    const float* Wq = (const float*)d_in[1];
    const float* bq = (const float*)d_in[2];
    const float* Wk = (const float*)d_in[3];
    const float* bk = (const float*)d_in[4];
    const float* Wv = (const float*)d_in[5];
    const float* bv = (const float*)d_in[6];
    const float* Wo = (const float*)d_in[7];
    const float* bo = (const float*)d_in[8];

    const size_t NE = (size_t)M_TOT * DM;        // 4M elems
    u16* xb     = (u16*)d_ws;                    //  8 MB  x bf16
    u16* wt_qkv = xb + NE;                       //  6 MB  [3][1024][1024] (n,k)
    u16* wt_o   = wt_qkv + 3 * (size_t)DM * DM;  //  2 MB
    u16* q_ws   = wt_o + (size_t)DM * DM;        //  8 MB  [bh][s][d]
    u16* k_ws   = q_ws + NE;                     //  8 MB  [bh][s][d]
    u16* vt_ws  = k_ws + NE;                     //  8 MB  [bh][d][s]
    u16* a_ws   = vt_ws + NE;                    //  8 MB  [4096][1024]

    cast_x<<<M_TOT * DM / 4 / 256, 256, 0, stream>>>((const float4*)x, (ushort4*)xb);
    transpose_cast4<<<dim3(32, 32, 4), 256, 0, stream>>>(Wq, Wk, Wv, Wo, wt_qkv);

    gemm_bt<<<dim3(24, 32), 256, 0, stream>>>(
        xb, wt_qkv, 1, bq, bk, bv, q_ws, k_ws, vt_ws);

    attn_mfma<<<dim3(BATCH * NH, SEQ / 128), 256, 0, stream>>>(
        q_ws, k_ws, vt_ws, a_ws);

    gemm_bt<<<dim3(8, 32), 256, 0, stream>>>(
        a_ws, wt_o, 0, bo, nullptr, nullptr, d_out, nullptr, nullptr);
}